// Round 13
// baseline (145.083 us; speedup 1.0000x reference)
//
#include <hip/hip_runtime.h>
#include <hip/hip_bf16.h>

// HSA prefill R24 (resubmit; R12 bench was a GPU-broker timeout, no data).
// R24: producer-side restructure (dedup the KV gather).
// R23 post-mortem: fp8 FAILED accuracy (0.172 > 0.0616) -> low-precision
// byte cuts are infeasible; revert P/V to bf16.
// Model (fits all data): per-CU memory throughput cap ~11 B/cy/CU
//   (main 1MB/CU = 39us ✓, fill 1.05MB/CU = 43.5us ✓, copy ubench
//   6.3TB/s/256CU = 10.2 B/cy ✓). Depth/placement/warm/occupancy can't
//   move a byte cap -> move fewer bytes ALGORITHMICALLY.
// Key: softmax is per-block -> each (l,s) contribution independent.
// Invert: producer block owns ONE KV block b (32KB, L1-resident),
// streams all (l,s) pairs referencing it (inverted index).
// Traffic 256MB -> Q 64MB + KV 4MB + ws 32MB(w)+32MB(r)+out 4MB.
// Kernels: pack_kv (R17) + pack_q + build_index + hsa_prod + hsa_red.
// Producer inner body = R17's verified wave-pair structure with
// baseA=baseB=b (K/V streams shared by both pairs), P bf16 in per-wave
// LDS slices, NO barriers, NO epilogue tree; per-pair direct bf16 store
// to ws; reducer sums 16 s-slices -> out.

namespace {

constexpr int kLq = 256, kHQ = 32, kH = 2, kG = 16, kD = 128, kS = 16;
constexpr int kNB = 64;
constexpr float kScaleLog2e = 0.08838834764831845f * 1.4426950408889634f;

constexpr int kKPackN = kH * kNB * 16 * 64;  // uint4 per kp/vp (2 MB each)
constexpr int kPStr   = 72;                  // P row stride (shorts)
constexpr int kSStr   = 136;                 // pack LDS row stride (shorts)
constexpr int kMaxE   = 512;                 // index capacity per (h,b)

// workspace byte offsets
constexpr size_t kOffKP   = 0;
constexpr size_t kOffVP   = kOffKP + (size_t)kKPackN * 16;          // +2MB
constexpr size_t kOffQP   = kOffVP + (size_t)kKPackN * 16;          // +2MB
constexpr size_t kOffCnt  = kOffQP + (size_t)kLq * kH * 4 * 64 * 16;// +2MB
constexpr size_t kOffList = kOffCnt + 4096;
constexpr size_t kOffWS   = kOffList + (size_t)kH * kNB * kMaxE * 4;

typedef short s16x8 __attribute__((ext_vector_type(8)));
typedef float f32x4 __attribute__((ext_vector_type(4)));

union U32BF2 { unsigned int u; __hip_bfloat162 h; };
union FragU  { uint4 u; s16x8 v; };

static __device__ inline unsigned int pk_bf16(float a, float b) {
    U32BF2 z; z.h = __float22bfloat162_rn(make_float2(a, b));
    return z.u;
}
static __device__ inline float bf_lo(unsigned int u) {
    return __uint_as_float(u << 16);
}
static __device__ inline float bf_hi(unsigned int u) {
    return __uint_as_float(u & 0xffff0000u);
}

#define MF(a, b, c) __builtin_amdgcn_mfma_f32_16x16x32_bf16(a, b, c, 0, 0, 0)

// ---------------- pack_kv (R17 verbatim) -----------------------------------
// K_packed idx = ((h*64+blk)*16 + t*4+st)*64 + lane (lane = quad*16+n)
//   holds K[u = blk*64 + t*16 + n][h][d = st*32 + quad*8 + j]
// V_packed idx = ((h*64+blk)*16 + dt*2+st)*64 + lane
//   holds V[u = blk*64 + st*32 + quad*8 + j][h][d = dt*16 + n]
__global__ __launch_bounds__(256)
void pack_kv(const float* __restrict__ k, const float* __restrict__ v,
             uint4* __restrict__ kp, uint4* __restrict__ vp)
{
    __shared__ unsigned short S_s[32 * kSStr];

    const int bid  = blockIdx.x;                 // 0..511
    const int isV  = bid & 1;
    const int half = (bid >> 1) & 1;
    const int blk  = (bid >> 2) & 63;
    const int h    = bid >> 8;
    const int t    = threadIdx.x;
    const int lane = t & 63, n = lane & 15, quad = lane >> 4;
    const int wv   = t >> 6;

    {
        const float* src = (isV ? v : k) +
            ((size_t)(blk * 64 + half * 32) * kH + h) * kD;
        const int r0 = t >> 5, c4 = (t & 31) << 2;
        #pragma unroll
        for (int p = 0; p < 4; ++p) {
            const int r = p * 8 + r0;
            const float4 f = *(const float4*)(src + (size_t)r * (kH * kD) + c4);
            *(unsigned int*)&S_s[r * kSStr + c4]     = pk_bf16(f.x, f.y);
            *(unsigned int*)&S_s[r * kSStr + c4 + 2] = pk_bf16(f.z, f.w);
        }
    }
    __syncthreads();

    const size_t obase = (size_t)(h * 64 + blk) * 16 * 64;
    if (!isV) {
        #pragma unroll
        for (int rep = 0; rep < 2; ++rep) {
            const int cl    = wv * 2 + rep;
            const int t_loc = cl >> 2, st = cl & 3;
            const int c     = (2 * half + t_loc) * 4 + st;
            const int u_loc = t_loc * 16 + n;
            kp[obase + (size_t)c * 64 + lane] =
                *(const uint4*)&S_s[u_loc * kSStr + st * 32 + quad * 8];
        }
    } else {
        #pragma unroll
        for (int rep = 0; rep < 2; ++rep) {
            const int dt = wv * 2 + rep;
            const int c  = dt * 2 + half;
            const int d  = dt * 16 + n;
            unsigned short s[8];
            #pragma unroll
            for (int j = 0; j < 8; ++j) s[j] = S_s[(quad * 8 + j) * kSStr + d];
            uint4 val;
            val.x = s[0] | ((unsigned)s[1] << 16);
            val.y = s[2] | ((unsigned)s[3] << 16);
            val.z = s[4] | ((unsigned)s[5] << 16);
            val.w = s[6] | ((unsigned)s[7] << 16);
            vp[obase + (size_t)c * 64 + lane] = val;
        }
    }
}

// ---------------- pack_q: Q -> bf16 B-frags --------------------------------
// qp idx = ((l*2+h)*4 + st)*64 + lane : uint4 = Q[l, h*16+n, st*32+quad*8 ..+7]
__global__ __launch_bounds__(256)
void pack_q(const float* __restrict__ q, uint4* __restrict__ qp)
{
    const int l    = blockIdx.x;                 // 0..255
    const int t    = threadIdx.x;
    const int lane = t & 63, n = lane & 15, quad = lane >> 4;
    const int st   = t >> 6;                     // 0..3
    #pragma unroll
    for (int h = 0; h < 2; ++h) {
        const float* qb = q + ((size_t)l * kHQ + h * kG + n) * kD
                            + st * 32 + quad * 8;
        const float4 f0 = *(const float4*)qb;
        const float4 f1 = *(const float4*)(qb + 4);
        uint4 z;
        z.x = pk_bf16(f0.x, f0.y); z.y = pk_bf16(f0.z, f0.w);
        z.z = pk_bf16(f1.x, f1.y); z.w = pk_bf16(f1.z, f1.w);
        qp[((size_t)(l * 2 + h) * 4 + st) * 64 + lane] = z;
    }
}

// ---------------- build_index: invert bidx ---------------------------------
// entry (l,h,s) with b = bidx[l,h,s] >= 0 -> glist[(h*64+b)*kMaxE + pos] =
// (l<<4)|s ; gcount[h*64+b] = count. Single block; LDS atomics.
__global__ __launch_bounds__(512)
void build_index(const int* __restrict__ bidx, int* __restrict__ gcount,
                 int* __restrict__ glist)
{
    __shared__ int cnt[kH * kNB];
    const int t = threadIdx.x;
    if (t < kH * kNB) cnt[t] = 0;
    __syncthreads();
    for (int id = t; id < kLq * kH * kS; id += 512) {
        const int b = bidx[id];
        if (b >= 0) {
            const int l = id >> 5, h = (id >> 4) & 1, s = id & 15;
            const int key = h * kNB + b;
            const int pos = atomicAdd(&cnt[key], 1);
            if (pos < kMaxE) glist[key * kMaxE + pos] = (l << 4) | s;
        }
    }
    __syncthreads();
    if (t < kH * kNB) gcount[t] = min(cnt[t], kMaxE);
}

// ---------------- producer -------------------------------------------------
__global__ __launch_bounds__(512, 4)
void hsa_prod(const uint4* __restrict__ qp, const float* __restrict__ w,
              const int* __restrict__ glist, const int* __restrict__ gcount,
              const uint4* __restrict__ kp, const uint4* __restrict__ vp,
              unsigned short* __restrict__ wsb)
{
    __shared__ __align__(16) unsigned char smem[36864];  // 8 waves x 4608 B

    const int p    = blockIdx.x;                 // 0..511 = h*256 + b*4 + chunk
    const int h    = p >> 8;
    const int b    = (p >> 2) & 63;
    const int chunk= p & 3;
    const int tid  = threadIdx.x;
    const int wave = tid >> 6;
    const int lane = tid & 63;
    const int n    = lane & 15;
    const int quad = lane >> 4;

    const int count  = gcount[h * kNB + b];
    const int baseKV = (h * kNB + b) * 1024;
    const int lbase  = (h * kNB + b) * kMaxE;

    unsigned short* PA = (unsigned short*)smem + wave * 2304;
    unsigned short* PB = PA + 1152;

    for (int j = 0; ; ++j) {
        const int eA = chunk + 4 * (j * 16 + wave * 2);
        if (eA >= count) break;
        const int eB   = eA + 4;
        const bool hasB = (eB < count);
        const int entA = glist[lbase + eA];
        const int entB = hasB ? glist[lbase + eB] : entA;
        const int lA = entA >> 4, sA = entA & 15;
        const int lB = entB >> 4, sB = entB & 15;
        const float wvA = w[((size_t)lA * kHQ + h * kG + n) * kS + sA];
        const float wvB = hasB ? w[((size_t)lB * kHQ + h * kG + n) * kS + sB] : 0.f;

        // Q frags (persistent regs) + K/V prologue (shared K/V streams)
        FragU aqA[4], aqB[4], kk[4], vr0[4], vr1[4];
        #pragma unroll
        for (int st = 0; st < 4; ++st)
            aqA[st].u = qp[((size_t)(lA * 2 + h) * 4 + st) * 64 + lane];
        #pragma unroll
        for (int st = 0; st < 4; ++st)
            aqB[st].u = qp[((size_t)(lB * 2 + h) * 4 + st) * 64 + lane];
        #pragma unroll
        for (int st = 0; st < 4; ++st) kk[st].u = kp[baseKV + st * 64 + lane];
        #pragma unroll
        for (int i = 0; i < 4; ++i)    vr0[i].u = vp[baseKV + i * 64 + lane];
        #pragma unroll
        for (int i = 0; i < 4; ++i)    vr1[i].u = vp[baseKV + (4 + i) * 64 + lane];
        __builtin_amdgcn_sched_barrier(0);

        // ---- scores: both pairs share the K stream ----
        float partA = 0.f, partB = 0.f;
        #pragma unroll
        for (int t = 0; t < 4; ++t) {
            f32x4 scA = {0.f, 0.f, 0.f, 0.f};
            f32x4 scB = {0.f, 0.f, 0.f, 0.f};
            #pragma unroll
            for (int st = 0; st < 4; ++st) scA = MF(kk[st].v, aqA[st].v, scA);
            #pragma unroll
            for (int st = 0; st < 4; ++st) scB = MF(kk[st].v, aqB[st].v, scB);
            if (t < 3) {
                #pragma unroll
                for (int st = 0; st < 4; ++st)
                    kk[st].u = kp[baseKV + ((t + 1) * 4 + st) * 64 + lane];
            }
            __builtin_amdgcn_sched_barrier(0);
            #pragma unroll
            for (int r = 0; r < 4; ++r) {
                scA[r] = exp2f(scA[r] * kScaleLog2e);
                partA += scA[r];
                scB[r] = exp2f(scB[r] * kScaleLog2e);
                partB += scB[r];
            }
            *(unsigned long long*)&PA[n * kPStr + t * 16 + quad * 4] =
                ((unsigned long long)pk_bf16(scA[2], scA[3]) << 32) |
                pk_bf16(scA[0], scA[1]);
            *(unsigned long long*)&PB[n * kPStr + t * 16 + quad * 4] =
                ((unsigned long long)pk_bf16(scB[2], scB[3]) << 32) |
                pk_bf16(scB[0], scB[1]);
        }

        // ---- denominators ----
        partA += __shfl_xor(partA, 16);
        partA += __shfl_xor(partA, 32);
        partB += __shfl_xor(partB, 16);
        partB += __shfl_xor(partB, 32);
        const float coefA = wvA / partA;
        const float coefB = wvB / partB;

        const f32x4 zero = {0.f, 0.f, 0.f, 0.f};
        f32x4 oacc[8];

        // ---- PV(A): vr0=c0-3, vr1=c4-7 in regs; refills keep stream warm ----
        {
            const s16x8 bf0 = *(const s16x8*)&PA[n * kPStr + quad * 8];
            const s16x8 bf1 = *(const s16x8*)&PA[n * kPStr + 32 + quad * 8];
            {   // vg0: c0-3 -> d-tiles 0,1 ; refill vr0 <- c8-11
                f32x4 p0 = MF(vr0[0].v, bf0, zero); p0 = MF(vr0[1].v, bf1, p0);
                f32x4 p1 = MF(vr0[2].v, bf0, zero); p1 = MF(vr0[3].v, bf1, p1);
                #pragma unroll
                for (int i = 0; i < 4; ++i) vr0[i].u = vp[baseKV + (8 + i) * 64 + lane];
                __builtin_amdgcn_sched_barrier(0);
                #pragma unroll
                for (int r = 0; r < 4; ++r) {
                    oacc[0][r] = coefA * p0[r];
                    oacc[1][r] = coefA * p1[r];
                }
            }
            {   // vg1: c4-7 -> d-tiles 2,3 ; refill vr1 <- c12-15
                f32x4 p0 = MF(vr1[0].v, bf0, zero); p0 = MF(vr1[1].v, bf1, p0);
                f32x4 p1 = MF(vr1[2].v, bf0, zero); p1 = MF(vr1[3].v, bf1, p1);
                #pragma unroll
                for (int i = 0; i < 4; ++i) vr1[i].u = vp[baseKV + (12 + i) * 64 + lane];
                __builtin_amdgcn_sched_barrier(0);
                #pragma unroll
                for (int r = 0; r < 4; ++r) {
                    oacc[2][r] = coefA * p0[r];
                    oacc[3][r] = coefA * p1[r];
                }
            }
            {   // vg2: c8-11 -> d-tiles 4,5 ; refill vr0 <- c0-3 (for B)
                f32x4 p0 = MF(vr0[0].v, bf0, zero); p0 = MF(vr0[1].v, bf1, p0);
                f32x4 p1 = MF(vr0[2].v, bf0, zero); p1 = MF(vr0[3].v, bf1, p1);
                #pragma unroll
                for (int i = 0; i < 4; ++i) vr0[i].u = vp[baseKV + i * 64 + lane];
                __builtin_amdgcn_sched_barrier(0);
                #pragma unroll
                for (int r = 0; r < 4; ++r) {
                    oacc[4][r] = coefA * p0[r];
                    oacc[5][r] = coefA * p1[r];
                }
            }
            {   // vg3: c12-15 -> d-tiles 6,7 ; refill vr1 <- c4-7 (for B)
                f32x4 p0 = MF(vr1[0].v, bf0, zero); p0 = MF(vr1[1].v, bf1, p0);
                f32x4 p1 = MF(vr1[2].v, bf0, zero); p1 = MF(vr1[3].v, bf1, p1);
                #pragma unroll
                for (int i = 0; i < 4; ++i) vr1[i].u = vp[baseKV + (4 + i) * 64 + lane];
                __builtin_amdgcn_sched_barrier(0);
                #pragma unroll
                for (int r = 0; r < 4; ++r) {
                    oacc[6][r] = coefA * p0[r];
                    oacc[7][r] = coefA * p1[r];
                }
            }
        }
        // store A contribution (bf16): ws[lA][h][sA][g=n][d]
        {
            const size_t base = (((size_t)(lA * 2 + h) * 16 + sA) * 16 + n) * 128;
            #pragma unroll
            for (int dt = 0; dt < 8; ++dt) {
                uint2 vv;
                vv.x = pk_bf16(oacc[dt][0], oacc[dt][1]);
                vv.y = pk_bf16(oacc[dt][2], oacc[dt][3]);
                *(uint2*)(wsb + base + dt * 16 + quad * 4) = vv;
            }
        }

        // ---- PV(B): same V chunks (L1-hot), P from PB ----
        {
            const s16x8 bf0 = *(const s16x8*)&PB[n * kPStr + quad * 8];
            const s16x8 bf1 = *(const s16x8*)&PB[n * kPStr + 32 + quad * 8];
            {   // vg0: c0-3 -> d 0,1 ; refill vr0 <- c8-11
                f32x4 p0 = MF(vr0[0].v, bf0, zero); p0 = MF(vr0[1].v, bf1, p0);
                f32x4 p1 = MF(vr0[2].v, bf0, zero); p1 = MF(vr0[3].v, bf1, p1);
                #pragma unroll
                for (int i = 0; i < 4; ++i) vr0[i].u = vp[baseKV + (8 + i) * 64 + lane];
                __builtin_amdgcn_sched_barrier(0);
                #pragma unroll
                for (int r = 0; r < 4; ++r) {
                    oacc[0][r] = coefB * p0[r];
                    oacc[1][r] = coefB * p1[r];
                }
            }
            {   // vg1: c4-7 -> d 2,3 ; refill vr1 <- c12-15
                f32x4 p0 = MF(vr1[0].v, bf0, zero); p0 = MF(vr1[1].v, bf1, p0);
                f32x4 p1 = MF(vr1[2].v, bf0, zero); p1 = MF(vr1[3].v, bf1, p1);
                #pragma unroll
                for (int i = 0; i < 4; ++i) vr1[i].u = vp[baseKV + (12 + i) * 64 + lane];
                __builtin_amdgcn_sched_barrier(0);
                #pragma unroll
                for (int r = 0; r < 4; ++r) {
                    oacc[2][r] = coefB * p0[r];
                    oacc[3][r] = coefB * p1[r];
                }
            }
            {   // vg2: c8-11 -> d 4,5
                f32x4 p0 = MF(vr0[0].v, bf0, zero); p0 = MF(vr0[1].v, bf1, p0);
                f32x4 p1 = MF(vr0[2].v, bf0, zero); p1 = MF(vr0[3].v, bf1, p1);
                #pragma unroll
                for (int r = 0; r < 4; ++r) {
                    oacc[4][r] = coefB * p0[r];
                    oacc[5][r] = coefB * p1[r];
                }
            }
            {   // vg3: c12-15 -> d 6,7
                f32x4 p0 = MF(vr1[0].v, bf0, zero); p0 = MF(vr1[1].v, bf1, p0);
                f32x4 p1 = MF(vr1[2].v, bf0, zero); p1 = MF(vr1[3].v, bf1, p1);
                #pragma unroll
                for (int r = 0; r < 4; ++r) {
                    oacc[6][r] = coefB * p0[r];
                    oacc[7][r] = coefB * p1[r];
                }
            }
        }
        if (hasB) {
            const size_t base = (((size_t)(lB * 2 + h) * 16 + sB) * 16 + n) * 128;
            #pragma unroll
            for (int dt = 0; dt < 8; ++dt) {
                uint2 vv;
                vv.x = pk_bf16(oacc[dt][0], oacc[dt][1]);
                vv.y = pk_bf16(oacc[dt][2], oacc[dt][3]);
                *(uint2*)(wsb + base + dt * 16 + quad * 4) = vv;
            }
        }
    }
}

// ---------------- reducer: out[l][h*16+g][d] = sum_s ws[l][h][s][g][d] -----
__global__ __launch_bounds__(256)
void hsa_red(const unsigned short* __restrict__ wsb,
             const int* __restrict__ bidx, float* __restrict__ out)
{
    const int p = blockIdx.x;                    // 0..511 = l*2 + h
    const int l = p >> 1, h = p & 1;
    const int t = threadIdx.x;
    const int g = t >> 4, dc = t & 15, d0 = dc * 8;

    __shared__ int valid[16];
    if (t < 16) valid[t] = bidx[(size_t)p * 16 + t];
    __syncthreads();

    float acc[8];
    #pragma unroll
    for (int r = 0; r < 8; ++r) acc[r] = 0.f;

    #pragma unroll
    for (int s = 0; s < 16; ++s) {
        if (valid[s] < 0) continue;
        const uint4 vv = *(const uint4*)(wsb +
            (((size_t)p * 16 + s) * 16 + g) * 128 + d0);
        acc[0] += bf_lo(vv.x); acc[1] += bf_hi(vv.x);
        acc[2] += bf_lo(vv.y); acc[3] += bf_hi(vv.y);
        acc[4] += bf_lo(vv.z); acc[5] += bf_hi(vv.z);
        acc[6] += bf_lo(vv.w); acc[7] += bf_hi(vv.w);
    }

    float* ob = out + ((size_t)l * kHQ + h * kG + g) * kD + d0;
    float4 o0, o1;
    o0.x = acc[0]; o0.y = acc[1]; o0.z = acc[2]; o0.w = acc[3];
    o1.x = acc[4]; o1.y = acc[5]; o1.z = acc[6]; o1.w = acc[7];
    *(float4*)ob       = o0;
    *(float4*)(ob + 4) = o1;
}

} // namespace

extern "C" void kernel_launch(void* const* d_in, const int* in_sizes, int n_in,
                              void* d_out, int out_size, void* d_ws, size_t ws_size,
                              hipStream_t stream)
{
    const float* q    = (const float*)d_in[0];
    const float* k    = (const float*)d_in[1];
    const float* v    = (const float*)d_in[2];
    const float* w    = (const float*)d_in[3];
    const int*   bidx = (const int*)d_in[4];
    float* out = (float*)d_out;

    char* ws = (char*)d_ws;
    uint4*          kp     = (uint4*)(ws + kOffKP);
    uint4*          vp     = (uint4*)(ws + kOffVP);
    uint4*          qp     = (uint4*)(ws + kOffQP);
    int*            gcount = (int*)(ws + kOffCnt);
    int*            glist  = (int*)(ws + kOffList);
    unsigned short* wsb    = (unsigned short*)(ws + kOffWS);

    pack_kv<<<dim3(512), dim3(256), 0, stream>>>(k, v, kp, vp);
    pack_q<<<dim3(256), dim3(256), 0, stream>>>(q, qp);
    build_index<<<dim3(1), dim3(512), 0, stream>>>(bidx, gcount, glist);
    hsa_prod<<<dim3(512), dim3(512), 0, stream>>>(qp, w, glist, gcount, kp, vp, wsb);
    hsa_red<<<dim3(512), dim3(256), 0, stream>>>(wsb, bidx, out);
}

// Round 14
// 143.802 us; speedup vs baseline: 1.0089x; 1.0089x over previous
//
#include <hip/hip_runtime.h>
#include <hip/hip_bf16.h>

// HSA prefill R25 = R24 + clean ws write path.
// R24 counters (GOLD): hsa_prod 53.7us, WRITE_SIZE=133MB + FETCH=73MB
// = 206MB HBM @4TB/s = 52us == observed -> producer is HBM-bound on
// WRITE AMPLIFICATION: old store scattered each wave's 4KB contribution
// as 8B pieces at 256B stride -> partial-line RMW (fetch+writeback per
// line). Also VGPR=64 again (4th time): compiler never grants deep
// streams; depth tuning was always noise. Algorithmic dedup worked
// (fetch << 256MB) and accuracy PASSED at 0.015625 (bf16-ws validated).
// R25 changes (stores/indexing only; producer math untouched):
//   (1) slot-compacted ws: prefix-sum over 128 (h,b) keys -> dense slot
//       per entry; wave stores its 4KB CONTIGUOUSLY (slot*4096 + dt*512
//       + lane*8) -> 512B/instr, full lines, no RMW.
//   (2) einv[id] (id -> slot) for the reducer; -1 = invalid; fixed
//       s-order summation -> deterministic.
//   (3) XCD-co-located chunks: p = chunk*128 + key -> all 4 chunks of a
//       KV block share one XCD's L2 (key mod 8 = XCD).
// Predict: prod WRITE ~35MB, FETCH ~35MB, 53.7 -> 15-20us; total ~75-80us
// (vs best 88.5). If prod >35us: VGPR-64 serial chain is the real bound
// -> revert to R22 and conclude.

namespace {

constexpr int kLq = 256, kHQ = 32, kH = 2, kG = 16, kD = 128, kS = 16;
constexpr int kNB = 64;
constexpr float kScaleLog2e = 0.08838834764831845f * 1.4426950408889634f;

constexpr int kKPackN = kH * kNB * 16 * 64;  // uint4 per kp/vp (2 MB each)
constexpr int kPStr   = 72;                  // P row stride (shorts)
constexpr int kSStr   = 136;                 // pack LDS row stride (shorts)
constexpr int kMaxE   = 512;                 // index capacity per (h,b)
constexpr int kNKey   = kH * kNB;            // 128
constexpr int kNId    = kLq * kH * kS;       // 8192

// workspace byte offsets
constexpr size_t kOffKP   = 0;
constexpr size_t kOffVP   = kOffKP + (size_t)kKPackN * 16;          // +2MB
constexpr size_t kOffQP   = kOffVP + (size_t)kKPackN * 16;          // +2MB
constexpr size_t kOffCnt  = kOffQP + (size_t)kLq * kH * 4 * 64 * 16;// +2MB
constexpr size_t kOffBase = kOffCnt + 512;
constexpr size_t kOffEinv = kOffBase + 512;
constexpr size_t kOffList = kOffEinv + (size_t)kNId * 4;
constexpr size_t kOffWS   = kOffList + (size_t)kNKey * kMaxE * 4;

typedef short s16x8 __attribute__((ext_vector_type(8)));
typedef float f32x4 __attribute__((ext_vector_type(4)));

union U32BF2 { unsigned int u; __hip_bfloat162 h; };
union FragU  { uint4 u; s16x8 v; };

static __device__ inline unsigned int pk_bf16(float a, float b) {
    U32BF2 z; z.h = __float22bfloat162_rn(make_float2(a, b));
    return z.u;
}
static __device__ inline float bf_lo(unsigned int u) {
    return __uint_as_float(u << 16);
}
static __device__ inline float bf_hi(unsigned int u) {
    return __uint_as_float(u & 0xffff0000u);
}

#define MF(a, b, c) __builtin_amdgcn_mfma_f32_16x16x32_bf16(a, b, c, 0, 0, 0)

// ---------------- pack_kv (R17 verbatim) -----------------------------------
// K_packed idx = ((h*64+blk)*16 + t*4+st)*64 + lane (lane = quad*16+n)
//   holds K[u = blk*64 + t*16 + n][h][d = st*32 + quad*8 + j]
// V_packed idx = ((h*64+blk)*16 + dt*2+st)*64 + lane
//   holds V[u = blk*64 + st*32 + quad*8 + j][h][d = dt*16 + n]
__global__ __launch_bounds__(256)
void pack_kv(const float* __restrict__ k, const float* __restrict__ v,
             uint4* __restrict__ kp, uint4* __restrict__ vp)
{
    __shared__ unsigned short S_s[32 * kSStr];

    const int bid  = blockIdx.x;                 // 0..511
    const int isV  = bid & 1;
    const int half = (bid >> 1) & 1;
    const int blk  = (bid >> 2) & 63;
    const int h    = bid >> 8;
    const int t    = threadIdx.x;
    const int lane = t & 63, n = lane & 15, quad = lane >> 4;
    const int wv   = t >> 6;

    {
        const float* src = (isV ? v : k) +
            ((size_t)(blk * 64 + half * 32) * kH + h) * kD;
        const int r0 = t >> 5, c4 = (t & 31) << 2;
        #pragma unroll
        for (int p = 0; p < 4; ++p) {
            const int r = p * 8 + r0;
            const float4 f = *(const float4*)(src + (size_t)r * (kH * kD) + c4);
            *(unsigned int*)&S_s[r * kSStr + c4]     = pk_bf16(f.x, f.y);
            *(unsigned int*)&S_s[r * kSStr + c4 + 2] = pk_bf16(f.z, f.w);
        }
    }
    __syncthreads();

    const size_t obase = (size_t)(h * 64 + blk) * 16 * 64;
    if (!isV) {
        #pragma unroll
        for (int rep = 0; rep < 2; ++rep) {
            const int cl    = wv * 2 + rep;
            const int t_loc = cl >> 2, st = cl & 3;
            const int c     = (2 * half + t_loc) * 4 + st;
            const int u_loc = t_loc * 16 + n;
            kp[obase + (size_t)c * 64 + lane] =
                *(const uint4*)&S_s[u_loc * kSStr + st * 32 + quad * 8];
        }
    } else {
        #pragma unroll
        for (int rep = 0; rep < 2; ++rep) {
            const int dt = wv * 2 + rep;
            const int c  = dt * 2 + half;
            const int d  = dt * 16 + n;
            unsigned short s[8];
            #pragma unroll
            for (int j = 0; j < 8; ++j) s[j] = S_s[(quad * 8 + j) * kSStr + d];
            uint4 val;
            val.x = s[0] | ((unsigned)s[1] << 16);
            val.y = s[2] | ((unsigned)s[3] << 16);
            val.z = s[4] | ((unsigned)s[5] << 16);
            val.w = s[6] | ((unsigned)s[7] << 16);
            vp[obase + (size_t)c * 64 + lane] = val;
        }
    }
}

// ---------------- pack_q: Q -> bf16 B-frags --------------------------------
// qp idx = ((l*2+h)*4 + st)*64 + lane : uint4 = Q[l, h*16+n, st*32+quad*8 ..+7]
__global__ __launch_bounds__(256)
void pack_q(const float* __restrict__ q, uint4* __restrict__ qp)
{
    const int l    = blockIdx.x;                 // 0..255
    const int t    = threadIdx.x;
    const int lane = t & 63, n = lane & 15, quad = lane >> 4;
    const int st   = t >> 6;                     // 0..3
    #pragma unroll
    for (int h = 0; h < 2; ++h) {
        const float* qb = q + ((size_t)l * kHQ + h * kG + n) * kD
                            + st * 32 + quad * 8;
        const float4 f0 = *(const float4*)qb;
        const float4 f1 = *(const float4*)(qb + 4);
        uint4 z;
        z.x = pk_bf16(f0.x, f0.y); z.y = pk_bf16(f0.z, f0.w);
        z.z = pk_bf16(f1.x, f1.y); z.w = pk_bf16(f1.z, f1.w);
        qp[((size_t)(l * 2 + h) * 4 + st) * 64 + lane] = z;
    }
}

// ---------------- build_index: invert bidx + prefix slots ------------------
// glist[key*kMaxE+pos] = (l<<4)|s ; gbase[key] = prefix sum of counts;
// einv[id] = gbase[key]+pos (dense slot) or -1. Single block.
__global__ __launch_bounds__(512)
void build_index(const int* __restrict__ bidx, int* __restrict__ gcount,
                 int* __restrict__ gbase, int* __restrict__ glist,
                 int* __restrict__ einv)
{
    __shared__ int cnt[kNKey];
    __shared__ int base_s[kNKey];
    const int t = threadIdx.x;
    if (t < kNKey) cnt[t] = 0;
    __syncthreads();
    for (int id = t; id < kNId; id += 512) {
        const int b = bidx[id];
        if (b >= 0) {
            const int h = (id >> 4) & 1;
            atomicAdd(&cnt[h * kNB + b], 1);
        }
    }
    __syncthreads();
    if (t == 0) {
        int acc = 0;
        for (int i = 0; i < kNKey; ++i) {
            base_s[i] = acc;
            acc += min(cnt[i], kMaxE);
        }
    }
    __syncthreads();
    if (t < kNKey) {
        gcount[t] = min(cnt[t], kMaxE);
        gbase[t]  = base_s[t];
        cnt[t]    = 0;
    }
    __syncthreads();
    for (int id = t; id < kNId; id += 512) {
        const int b = bidx[id];
        if (b < 0) { einv[id] = -1; continue; }
        const int l = id >> 5, h = (id >> 4) & 1, s = id & 15;
        const int key = h * kNB + b;
        const int pos = atomicAdd(&cnt[key], 1);
        if (pos < kMaxE) {
            glist[key * kMaxE + pos] = (l << 4) | s;
            einv[id] = base_s[key] + pos;
        } else {
            einv[id] = -1;
        }
    }
}

// ---------------- producer -------------------------------------------------
__global__ __launch_bounds__(512, 4)
void hsa_prod(const uint4* __restrict__ qp, const float* __restrict__ w,
              const int* __restrict__ glist, const int* __restrict__ gcount,
              const int* __restrict__ gbase, const uint4* __restrict__ kp,
              const uint4* __restrict__ vp, unsigned short* __restrict__ wsb)
{
    __shared__ __align__(16) unsigned char smem[36864];  // 8 waves x 4608 B

    const int p    = blockIdx.x;                 // chunk*128 + key
    const int chunk= p >> 7;                     // 0..3
    const int key  = p & 127;                    // h*64+b ; key%8 = XCD
    const int h    = key >> 6;
    const int b    = key & 63;
    const int tid  = threadIdx.x;
    const int wave = tid >> 6;
    const int lane = tid & 63;
    const int n    = lane & 15;
    const int quad = lane >> 4;

    const int count  = gcount[key];
    const int gb     = gbase[key];
    const int baseKV = key * 1024;
    const int lbase  = key * kMaxE;

    unsigned short* PA = (unsigned short*)smem + wave * 2304;
    unsigned short* PB = PA + 1152;

    for (int j = 0; ; ++j) {
        const int eA = chunk + 4 * (j * 16 + wave * 2);
        if (eA >= count) break;
        const int eB   = eA + 4;
        const bool hasB = (eB < count);
        const int entA = glist[lbase + eA];
        const int entB = hasB ? glist[lbase + eB] : entA;
        const int lA = entA >> 4, sA = entA & 15;
        const int lB = entB >> 4, sB = entB & 15;
        const float wvA = w[((size_t)lA * kHQ + h * kG + n) * kS + sA];
        const float wvB = hasB ? w[((size_t)lB * kHQ + h * kG + n) * kS + sB] : 0.f;

        // Q frags (persistent regs) + K/V prologue (shared K/V streams)
        FragU aqA[4], aqB[4], kk[4], vr0[4], vr1[4];
        #pragma unroll
        for (int st = 0; st < 4; ++st)
            aqA[st].u = qp[((size_t)(lA * 2 + h) * 4 + st) * 64 + lane];
        #pragma unroll
        for (int st = 0; st < 4; ++st)
            aqB[st].u = qp[((size_t)(lB * 2 + h) * 4 + st) * 64 + lane];
        #pragma unroll
        for (int st = 0; st < 4; ++st) kk[st].u = kp[baseKV + st * 64 + lane];
        #pragma unroll
        for (int i = 0; i < 4; ++i)    vr0[i].u = vp[baseKV + i * 64 + lane];
        #pragma unroll
        for (int i = 0; i < 4; ++i)    vr1[i].u = vp[baseKV + (4 + i) * 64 + lane];
        __builtin_amdgcn_sched_barrier(0);

        // ---- scores: both pairs share the K stream ----
        float partA = 0.f, partB = 0.f;
        #pragma unroll
        for (int t = 0; t < 4; ++t) {
            f32x4 scA = {0.f, 0.f, 0.f, 0.f};
            f32x4 scB = {0.f, 0.f, 0.f, 0.f};
            #pragma unroll
            for (int st = 0; st < 4; ++st) scA = MF(kk[st].v, aqA[st].v, scA);
            #pragma unroll
            for (int st = 0; st < 4; ++st) scB = MF(kk[st].v, aqB[st].v, scB);
            if (t < 3) {
                #pragma unroll
                for (int st = 0; st < 4; ++st)
                    kk[st].u = kp[baseKV + ((t + 1) * 4 + st) * 64 + lane];
            }
            __builtin_amdgcn_sched_barrier(0);
            #pragma unroll
            for (int r = 0; r < 4; ++r) {
                scA[r] = exp2f(scA[r] * kScaleLog2e);
                partA += scA[r];
                scB[r] = exp2f(scB[r] * kScaleLog2e);
                partB += scB[r];
            }
            *(unsigned long long*)&PA[n * kPStr + t * 16 + quad * 4] =
                ((unsigned long long)pk_bf16(scA[2], scA[3]) << 32) |
                pk_bf16(scA[0], scA[1]);
            *(unsigned long long*)&PB[n * kPStr + t * 16 + quad * 4] =
                ((unsigned long long)pk_bf16(scB[2], scB[3]) << 32) |
                pk_bf16(scB[0], scB[1]);
        }

        // ---- denominators ----
        partA += __shfl_xor(partA, 16);
        partA += __shfl_xor(partA, 32);
        partB += __shfl_xor(partB, 16);
        partB += __shfl_xor(partB, 32);
        const float coefA = wvA / partA;
        const float coefB = wvB / partB;

        const f32x4 zero = {0.f, 0.f, 0.f, 0.f};
        f32x4 oacc[8];

        // ---- PV(A) ----
        {
            const s16x8 bf0 = *(const s16x8*)&PA[n * kPStr + quad * 8];
            const s16x8 bf1 = *(const s16x8*)&PA[n * kPStr + 32 + quad * 8];
            {   // vg0: c0-3 -> d-tiles 0,1 ; refill vr0 <- c8-11
                f32x4 p0 = MF(vr0[0].v, bf0, zero); p0 = MF(vr0[1].v, bf1, p0);
                f32x4 p1 = MF(vr0[2].v, bf0, zero); p1 = MF(vr0[3].v, bf1, p1);
                #pragma unroll
                for (int i = 0; i < 4; ++i) vr0[i].u = vp[baseKV + (8 + i) * 64 + lane];
                __builtin_amdgcn_sched_barrier(0);
                #pragma unroll
                for (int r = 0; r < 4; ++r) {
                    oacc[0][r] = coefA * p0[r];
                    oacc[1][r] = coefA * p1[r];
                }
            }
            {   // vg1: c4-7 -> d-tiles 2,3 ; refill vr1 <- c12-15
                f32x4 p0 = MF(vr1[0].v, bf0, zero); p0 = MF(vr1[1].v, bf1, p0);
                f32x4 p1 = MF(vr1[2].v, bf0, zero); p1 = MF(vr1[3].v, bf1, p1);
                #pragma unroll
                for (int i = 0; i < 4; ++i) vr1[i].u = vp[baseKV + (12 + i) * 64 + lane];
                __builtin_amdgcn_sched_barrier(0);
                #pragma unroll
                for (int r = 0; r < 4; ++r) {
                    oacc[2][r] = coefA * p0[r];
                    oacc[3][r] = coefA * p1[r];
                }
            }
            {   // vg2: c8-11 -> d-tiles 4,5 ; refill vr0 <- c0-3 (for B)
                f32x4 p0 = MF(vr0[0].v, bf0, zero); p0 = MF(vr0[1].v, bf1, p0);
                f32x4 p1 = MF(vr0[2].v, bf0, zero); p1 = MF(vr0[3].v, bf1, p1);
                #pragma unroll
                for (int i = 0; i < 4; ++i) vr0[i].u = vp[baseKV + i * 64 + lane];
                __builtin_amdgcn_sched_barrier(0);
                #pragma unroll
                for (int r = 0; r < 4; ++r) {
                    oacc[4][r] = coefA * p0[r];
                    oacc[5][r] = coefA * p1[r];
                }
            }
            {   // vg3: c12-15 -> d-tiles 6,7 ; refill vr1 <- c4-7 (for B)
                f32x4 p0 = MF(vr1[0].v, bf0, zero); p0 = MF(vr1[1].v, bf1, p0);
                f32x4 p1 = MF(vr1[2].v, bf0, zero); p1 = MF(vr1[3].v, bf1, p1);
                #pragma unroll
                for (int i = 0; i < 4; ++i) vr1[i].u = vp[baseKV + (4 + i) * 64 + lane];
                __builtin_amdgcn_sched_barrier(0);
                #pragma unroll
                for (int r = 0; r < 4; ++r) {
                    oacc[6][r] = coefA * p0[r];
                    oacc[7][r] = coefA * p1[r];
                }
            }
        }
        // store A contribution: CONTIGUOUS 4KB at slot gb+eA
        {
            unsigned short* dst = wsb + (size_t)(gb + eA) * 2048 + lane * 4;
            #pragma unroll
            for (int dt = 0; dt < 8; ++dt) {
                uint2 vv;
                vv.x = pk_bf16(oacc[dt][0], oacc[dt][1]);
                vv.y = pk_bf16(oacc[dt][2], oacc[dt][3]);
                *(uint2*)(dst + dt * 256) = vv;
            }
        }

        // ---- PV(B): same V chunks (L1-hot), P from PB ----
        {
            const s16x8 bf0 = *(const s16x8*)&PB[n * kPStr + quad * 8];
            const s16x8 bf1 = *(const s16x8*)&PB[n * kPStr + 32 + quad * 8];
            {   // vg0: c0-3 -> d 0,1 ; refill vr0 <- c8-11
                f32x4 p0 = MF(vr0[0].v, bf0, zero); p0 = MF(vr0[1].v, bf1, p0);
                f32x4 p1 = MF(vr0[2].v, bf0, zero); p1 = MF(vr0[3].v, bf1, p1);
                #pragma unroll
                for (int i = 0; i < 4; ++i) vr0[i].u = vp[baseKV + (8 + i) * 64 + lane];
                __builtin_amdgcn_sched_barrier(0);
                #pragma unroll
                for (int r = 0; r < 4; ++r) {
                    oacc[0][r] = coefB * p0[r];
                    oacc[1][r] = coefB * p1[r];
                }
            }
            {   // vg1: c4-7 -> d 2,3 ; refill vr1 <- c12-15
                f32x4 p0 = MF(vr1[0].v, bf0, zero); p0 = MF(vr1[1].v, bf1, p0);
                f32x4 p1 = MF(vr1[2].v, bf0, zero); p1 = MF(vr1[3].v, bf1, p1);
                #pragma unroll
                for (int i = 0; i < 4; ++i) vr1[i].u = vp[baseKV + (12 + i) * 64 + lane];
                __builtin_amdgcn_sched_barrier(0);
                #pragma unroll
                for (int r = 0; r < 4; ++r) {
                    oacc[2][r] = coefB * p0[r];
                    oacc[3][r] = coefB * p1[r];
                }
            }
            {   // vg2: c8-11 -> d 4,5
                f32x4 p0 = MF(vr0[0].v, bf0, zero); p0 = MF(vr0[1].v, bf1, p0);
                f32x4 p1 = MF(vr0[2].v, bf0, zero); p1 = MF(vr0[3].v, bf1, p1);
                #pragma unroll
                for (int r = 0; r < 4; ++r) {
                    oacc[4][r] = coefB * p0[r];
                    oacc[5][r] = coefB * p1[r];
                }
            }
            {   // vg3: c12-15 -> d 6,7
                f32x4 p0 = MF(vr1[0].v, bf0, zero); p0 = MF(vr1[1].v, bf1, p0);
                f32x4 p1 = MF(vr1[2].v, bf0, zero); p1 = MF(vr1[3].v, bf1, p1);
                #pragma unroll
                for (int r = 0; r < 4; ++r) {
                    oacc[6][r] = coefB * p0[r];
                    oacc[7][r] = coefB * p1[r];
                }
            }
        }
        if (hasB) {
            unsigned short* dst = wsb + (size_t)(gb + eB) * 2048 + lane * 4;
            #pragma unroll
            for (int dt = 0; dt < 8; ++dt) {
                uint2 vv;
                vv.x = pk_bf16(oacc[dt][0], oacc[dt][1]);
                vv.y = pk_bf16(oacc[dt][2], oacc[dt][3]);
                *(uint2*)(dst + dt * 256) = vv;
            }
        }
    }
}

// ---------------- reducer: out[l][h*16+g][d] = sum_s ws[slot(l,h,s)] -------
// ws slot layout (shorts): slot*2048 + dt*256 + lane*4 where lane=quad*16+g,
// element (g, d = dt*16 + quad*4 + r).
__global__ __launch_bounds__(256)
void hsa_red(const unsigned short* __restrict__ wsb,
             const int* __restrict__ einv, float* __restrict__ out)
{
    const int p = blockIdx.x;                    // 0..511 = l*2 + h
    const int l = p >> 1, h = p & 1;
    const int t = threadIdx.x;
    const int g = t >> 4, dc = t & 15;
    const int dt = dc >> 1;
    const int la = ((dc & 1) * 2) * 16 + g;      // quad qa = (dc&1)*2

    __shared__ int es[16];
    if (t < 16) es[t] = einv[(size_t)p * 16 + t];
    __syncthreads();

    float acc[8];
    #pragma unroll
    for (int r = 0; r < 8; ++r) acc[r] = 0.f;

    #pragma unroll
    for (int s = 0; s < 16; ++s) {
        const int e = es[s];
        if (e < 0) continue;
        const unsigned short* src = wsb + (size_t)e * 2048 + dt * 256 + la * 4;
        const uint2 v0 = *(const uint2*)src;          // quad qa   -> d = dc*8+0..3
        const uint2 v1 = *(const uint2*)(src + 64);   // quad qa+1 -> d = dc*8+4..7
        acc[0] += bf_lo(v0.x); acc[1] += bf_hi(v0.x);
        acc[2] += bf_lo(v0.y); acc[3] += bf_hi(v0.y);
        acc[4] += bf_lo(v1.x); acc[5] += bf_hi(v1.x);
        acc[6] += bf_lo(v1.y); acc[7] += bf_hi(v1.y);
    }

    float* ob = out + ((size_t)l * kHQ + h * kG + g) * kD + dc * 8;
    float4 o0, o1;
    o0.x = acc[0]; o0.y = acc[1]; o0.z = acc[2]; o0.w = acc[3];
    o1.x = acc[4]; o1.y = acc[5]; o1.z = acc[6]; o1.w = acc[7];
    *(float4*)ob       = o0;
    *(float4*)(ob + 4) = o1;
}

} // namespace

extern "C" void kernel_launch(void* const* d_in, const int* in_sizes, int n_in,
                              void* d_out, int out_size, void* d_ws, size_t ws_size,
                              hipStream_t stream)
{
    const float* q    = (const float*)d_in[0];
    const float* k    = (const float*)d_in[1];
    const float* v    = (const float*)d_in[2];
    const float* w    = (const float*)d_in[3];
    const int*   bidx = (const int*)d_in[4];
    float* out = (float*)d_out;

    char* ws = (char*)d_ws;
    uint4*          kp     = (uint4*)(ws + kOffKP);
    uint4*          vp     = (uint4*)(ws + kOffVP);
    uint4*          qp     = (uint4*)(ws + kOffQP);
    int*            gcount = (int*)(ws + kOffCnt);
    int*            gbase  = (int*)(ws + kOffBase);
    int*            einv   = (int*)(ws + kOffEinv);
    int*            glist  = (int*)(ws + kOffList);
    unsigned short* wsb    = (unsigned short*)(ws + kOffWS);

    pack_kv<<<dim3(512), dim3(256), 0, stream>>>(k, v, kp, vp);
    pack_q<<<dim3(256), dim3(256), 0, stream>>>(q, qp);
    build_index<<<dim3(1), dim3(512), 0, stream>>>(bidx, gcount, gbase, glist, einv);
    hsa_prod<<<dim3(512), dim3(512), 0, stream>>>(qp, w, glist, gcount, gbase, kp, vp, wsb);
    hsa_red<<<dim3(512), dim3(256), 0, stream>>>(wsb, einv, out);
}

// Round 15
// 89.041 us; speedup vs baseline: 1.6294x; 1.6150x over previous
//
#include <hip/hip_runtime.h>
#include <hip/hip_bf16.h>

// HSA prefill R26 = R22 restored (best measured: 88.51us, Round 9, PASS).
// Session conclusion after R24/R25 (producer-dedup, 145/143.8us): the
// 5-kernel pipeline's fixed costs (harness fill ~46us every iter, 4 drain
// gaps, build_index, reducer, ws round-trip) exceed the gather savings even
// with clean full-line ws stores (R25: prod <47us but total unchanged).
// Final model (fits all 9 measurements): main = 256MB cache-resident gather
// at ~10-11 B/cy/CU == the chip's practical per-CU memory-path ceiling
// (same per-CU rate as the 6.3TB/s copy ubench; FETCH only ~15MB -> data
// is L2/L3-resident; the cap is the CU miss-slot/fill path, not DRAM).
// Levers exhausted: depth (R16/R19/R21 - allocator pins 64 VGPR, 4x),
// placement (R18/R22 neutral x2), warm (R22 neutral - same capped pipe),
// fp8 (R23 FAILS accuracy 0.172>0.0616), dedup (R24/R25 worse).
// This kernel: R17 body + XCD-h swizzle + L2 warm + pack alignment
// (all individually neutral, kept from the best-measured configuration).

namespace {

constexpr int kLq = 256, kHQ = 32, kH = 2, kG = 16, kD = 128, kS = 16;
constexpr int kNB = 64;                    // Lkv/BS: distinct blocks per head
constexpr float kScaleLog2e = 0.08838834764831845f * 1.4426950408889634f;

constexpr int kKPackN = kH * kNB * 16 * 64;  // uint4 elems per array (2 MB)
constexpr int kPStr   = 72;                  // P row stride (shorts)
constexpr int kSStr   = 136;                 // pack LDS row stride (shorts)

// main-kernel LDS layout (bytes):
//   [0, 32768)        qf slices:  wave*4096 + st*1024 + lane*16   (epilogue reuse)
//   [32768, 69632)    P slices:   wave*4608 + blk*2304 + (n*72+u)*2
constexpr int kQOff = 0;
constexpr int kPOff = 32768;

typedef short s16x8 __attribute__((ext_vector_type(8)));
typedef float f32x4 __attribute__((ext_vector_type(4)));

union U32BF2 { unsigned int u; __hip_bfloat162 h; };
union FragU  { uint4 u; s16x8 v; };

static __device__ inline unsigned int pk_bf16(float a, float b) {
    U32BF2 z; z.h = __float22bfloat162_rn(make_float2(a, b));
    return z.u;
}

// ---------------- pack kernel (R17 body; XCD-h-aligned work mapping) -------
// K_packed idx = ((h*64+blk)*16 + t*4+st)*64 + lane (lane = quad*16+n)
//   holds K[u = blk*64 + t*16 + n][h][d = st*32 + quad*8 + j]
// V_packed idx = ((h*64+blk)*16 + dt*2+st)*64 + lane
//   holds V[u = blk*64 + st*32 + quad*8 + j][h][d = dt*16 + n]
__global__ __launch_bounds__(256)
void pack_kv(const float* __restrict__ k, const float* __restrict__ v,
             uint4* __restrict__ kp, uint4* __restrict__ vp)
{
    __shared__ unsigned short S_s[32 * kSStr];   // 8.7 KB bf16 [u_loc][d]

    const int bid  = blockIdx.x;                 // 0..511
    // XCD-aligned mapping: xcd = bid&7 (dispatch round-robin); h = xcd>>2
    // so head h's pack blocks run on the XCD half that later reads them.
    const int xcd  = bid & 7;
    const int h    = xcd >> 2;
    const int idx  = (bid >> 3) * 4 + (xcd & 3); // 0..255, bijective
    const int isV  = idx & 1;
    const int half = (idx >> 1) & 1;
    const int blk  = idx >> 2;                   // 0..63
    const int t    = threadIdx.x;
    const int lane = t & 63, n = lane & 15, quad = lane >> 4;
    const int wv   = t >> 6;                     // 0..3

    {   // coalesced load 32 rows x 128 fp32 -> bf16 LDS
        const float* src = (isV ? v : k) +
            ((size_t)(blk * 64 + half * 32) * kH + h) * kD;
        const int r0 = t >> 5, c4 = (t & 31) << 2;
        #pragma unroll
        for (int p = 0; p < 4; ++p) {
            const int r = p * 8 + r0;
            const float4 f = *(const float4*)(src + (size_t)r * (kH * kD) + c4);
            *(unsigned int*)&S_s[r * kSStr + c4]     = pk_bf16(f.x, f.y);
            *(unsigned int*)&S_s[r * kSStr + c4 + 2] = pk_bf16(f.z, f.w);
        }
    }
    __syncthreads();

    const size_t obase = (size_t)(h * 64 + blk) * 16 * 64;
    if (!isV) {
        #pragma unroll
        for (int rep = 0; rep < 2; ++rep) {
            const int cl    = wv * 2 + rep;      // 0..7
            const int t_loc = cl >> 2, st = cl & 3;
            const int c     = (2 * half + t_loc) * 4 + st;
            const int u_loc = t_loc * 16 + n;
            kp[obase + (size_t)c * 64 + lane] =
                *(const uint4*)&S_s[u_loc * kSStr + st * 32 + quad * 8];
        }
    } else {
        #pragma unroll
        for (int rep = 0; rep < 2; ++rep) {
            const int dt = wv * 2 + rep;         // 0..7
            const int c  = dt * 2 + half;
            const int d  = dt * 16 + n;
            unsigned short s[8];
            #pragma unroll
            for (int j = 0; j < 8; ++j) s[j] = S_s[(quad * 8 + j) * kSStr + d];
            uint4 val;
            val.x = s[0] | ((unsigned)s[1] << 16);
            val.y = s[2] | ((unsigned)s[3] << 16);
            val.z = s[4] | ((unsigned)s[5] << 16);
            val.w = s[6] | ((unsigned)s[7] << 16);
            vp[obase + (size_t)c * 64 + lane] = val;
        }
    }
}

// ---------------- main kernel --------------------------------------------
__global__ __launch_bounds__(512, 4)
void hsa_main(const float* __restrict__ q, const float* __restrict__ w,
              const int* __restrict__ bidx, const uint4* __restrict__ kp,
              const uint4* __restrict__ vp, float* __restrict__ out)
{
    __shared__ __align__(16) unsigned char smem[69632];   // 68 KB (see layout)

    const int bid  = blockIdx.x;                 // 0..511
    // XCD-h swizzle: XCDs 0-3 handle h=0, XCDs 4-7 handle h=1 ->
    // per-XCD KV hot set is one head's kp+vp = 2 MB (< 4 MB L2).
    const int xcd  = bid & 7;
    const int h    = xcd >> 2;
    const int l    = (bid >> 3) * 4 + (xcd & 3);
    const int tid  = threadIdx.x;
    const int wave = tid >> 6;                   // 0..7
    const int lane = tid & 63;
    const int n    = lane & 15;
    const int quad = lane >> 4;

    // ---- L2 warm: fire-and-forget this block's 32 KB slice of the XCD's
    //      2 MB KV set (64 blocks/XCD cover it all in parallel). ----
    unsigned warmacc;
    {
        const int widx = bid >> 3;               // 0..63: slice within XCD
        const uint4* kph = kp + (size_t)h * 65536 + (size_t)widx * 1024;
        const uint4* vph = vp + (size_t)h * 65536 + (size_t)widx * 1024;
        const uint4 a0 = kph[tid];
        const uint4 a1 = kph[512 + tid];
        const uint4 b0 = vph[tid];
        const uint4 b1 = vph[512 + tid];
        warmacc = a0.x ^ a1.x ^ b0.x ^ b1.x;
    }
    __builtin_amdgcn_sched_barrier(0);           // pin warm issue first

    // ---- Q B-frags -> per-wave LDS slice (frees 16 VGPR) ----
    unsigned char* qlds = smem + kQOff + wave * 4096 + lane * 16;
    {
        const float* qb = q + ((size_t)l * kHQ + h * kG + n) * kD + quad * 8;
        #pragma unroll
        for (int st = 0; st < 4; ++st) {
            const float4 f0 = *(const float4*)(qb + st * 32);
            const float4 f1 = *(const float4*)(qb + st * 32 + 4);
            uint4 z;
            z.x = pk_bf16(f0.x, f0.y); z.y = pk_bf16(f0.z, f0.w);
            z.z = pk_bf16(f1.x, f1.y); z.w = pk_bf16(f1.z, f1.w);
            *(uint4*)(qlds + st * 1024) = z;
        }
    }

    // this wave's 2 s-blocks A,B: s = wave*2 + {0,1}
    int   baseA, baseB;
    float wvalA, wvalB;
    {
        const int sA = wave * 2, sB = wave * 2 + 1;
        const int biA = bidx[(size_t)(l * kH + h) * kS + sA];
        const int biB = bidx[(size_t)(l * kH + h) * kS + sB];
        wvalA = (biA < 0) ? 0.f : w[((size_t)l * kHQ + h * kG + n) * kS + sA];
        wvalB = (biB < 0) ? 0.f : w[((size_t)l * kHQ + h * kG + n) * kS + sB];
        baseA = (h * kNB + max(biA, 0)) * 1024;
        baseB = (h * kNB + max(biB, 0)) * 1024;
    }

    unsigned short* PA = (unsigned short*)(smem + kPOff + wave * 4608);
    unsigned short* PB = PA + kG * kPStr;

    // prologue: kA <- A-K-g0, kB <- B-K-g0, vrA <- A-V-g0, vrB <- A-V-g1
    // (16 loads in flight; vr banks drain under the scores phase)
    FragU kA[4], kB[4], vrA[4], vrB[4];
    #pragma unroll
    for (int st = 0; st < 4; ++st) kA[st].u = kp[baseA + st * 64 + lane];
    #pragma unroll
    for (int st = 0; st < 4; ++st) kB[st].u = kp[baseB + st * 64 + lane];
    #pragma unroll
    for (int i = 0; i < 4; ++i)    vrA[i].u = vp[baseA + i * 64 + lane];
    #pragma unroll
    for (int i = 0; i < 4; ++i)    vrB[i].u = vp[baseA + (4 + i) * 64 + lane];
    __builtin_amdgcn_sched_barrier(0);

    f32x4 oacc[8];
    #pragma unroll
    for (int dt = 0; dt < 8; ++dt) oacc[dt] = (f32x4){0.f, 0.f, 0.f, 0.f};

    // ---- interleaved scores: A-t, B-t alternate (refill distance ~1 group) ----
    float partA = 0.f, partB = 0.f;
    #pragma unroll
    for (int t = 0; t < 4; ++t) {
        {   // A group t
            f32x4 sc = {0.f, 0.f, 0.f, 0.f};
            #pragma unroll
            for (int st = 0; st < 4; ++st) {
                const s16x8 aq = *(const s16x8*)(qlds + st * 1024);
                sc = __builtin_amdgcn_mfma_f32_16x16x32_bf16(kA[st].v, aq, sc, 0, 0, 0);
            }
            if (t < 3) {
                #pragma unroll
                for (int st = 0; st < 4; ++st)
                    kA[st].u = kp[baseA + ((t + 1) * 4 + st) * 64 + lane];
            }
            __builtin_amdgcn_sched_barrier(0);
            #pragma unroll
            for (int r = 0; r < 4; ++r) {
                sc[r] = exp2f(sc[r] * kScaleLog2e);
                partA += sc[r];
            }
            const unsigned long long pq =
                ((unsigned long long)pk_bf16(sc[2], sc[3]) << 32) | pk_bf16(sc[0], sc[1]);
            *(unsigned long long*)&PA[n * kPStr + t * 16 + quad * 4] = pq;
        }
        {   // B group t
            f32x4 sc = {0.f, 0.f, 0.f, 0.f};
            #pragma unroll
            for (int st = 0; st < 4; ++st) {
                const s16x8 aq = *(const s16x8*)(qlds + st * 1024);
                sc = __builtin_amdgcn_mfma_f32_16x16x32_bf16(kB[st].v, aq, sc, 0, 0, 0);
            }
            if (t < 3) {
                #pragma unroll
                for (int st = 0; st < 4; ++st)
                    kB[st].u = kp[baseB + ((t + 1) * 4 + st) * 64 + lane];
            }
            __builtin_amdgcn_sched_barrier(0);
            #pragma unroll
            for (int r = 0; r < 4; ++r) {
                sc[r] = exp2f(sc[r] * kScaleLog2e);
                partB += sc[r];
            }
            const unsigned long long pq =
                ((unsigned long long)pk_bf16(sc[2], sc[3]) << 32) | pk_bf16(sc[0], sc[1]);
            *(unsigned long long*)&PB[n * kPStr + t * 16 + quad * 4] = pq;
        }
    }

    // ---- intra-wave denominators ----
    partA += __shfl_xor(partA, 16);
    partA += __shfl_xor(partA, 32);
    partB += __shfl_xor(partB, 16);
    partB += __shfl_xor(partB, 32);
    const float coefA = wvalA / partA;
    const float coefB = wvalB / partB;

    const f32x4 zero = {0.f, 0.f, 0.f, 0.f};

    // ---- PV(A): banks alternate; refill distance = 2 V-groups ----
    {
        const s16x8 bf0 = *(const s16x8*)&PA[n * kPStr + quad * 8];
        const s16x8 bf1 = *(const s16x8*)&PA[n * kPStr + 32 + quad * 8];

        // vg0: vrA = A-g0 -> d-tiles 0,1 ; refill vrA <- A-g2
        {
            f32x4 p0 = __builtin_amdgcn_mfma_f32_16x16x32_bf16(vrA[0].v, bf0, zero, 0, 0, 0);
            p0       = __builtin_amdgcn_mfma_f32_16x16x32_bf16(vrA[1].v, bf1, p0,   0, 0, 0);
            f32x4 p1 = __builtin_amdgcn_mfma_f32_16x16x32_bf16(vrA[2].v, bf0, zero, 0, 0, 0);
            p1       = __builtin_amdgcn_mfma_f32_16x16x32_bf16(vrA[3].v, bf1, p1,   0, 0, 0);
            #pragma unroll
            for (int i = 0; i < 4; ++i) vrA[i].u = vp[baseA + (8 + i) * 64 + lane];
            __builtin_amdgcn_sched_barrier(0);
            #pragma unroll
            for (int r = 0; r < 4; ++r) {
                oacc[0][r] = fmaf(coefA, p0[r], oacc[0][r]);
                oacc[1][r] = fmaf(coefA, p1[r], oacc[1][r]);
            }
        }
        // vg1: vrB = A-g1 -> d-tiles 2,3 ; refill vrB <- A-g3
        {
            f32x4 p0 = __builtin_amdgcn_mfma_f32_16x16x32_bf16(vrB[0].v, bf0, zero, 0, 0, 0);
            p0       = __builtin_amdgcn_mfma_f32_16x16x32_bf16(vrB[1].v, bf1, p0,   0, 0, 0);
            f32x4 p1 = __builtin_amdgcn_mfma_f32_16x16x32_bf16(vrB[2].v, bf0, zero, 0, 0, 0);
            p1       = __builtin_amdgcn_mfma_f32_16x16x32_bf16(vrB[3].v, bf1, p1,   0, 0, 0);
            #pragma unroll
            for (int i = 0; i < 4; ++i) vrB[i].u = vp[baseA + (12 + i) * 64 + lane];
            __builtin_amdgcn_sched_barrier(0);
            #pragma unroll
            for (int r = 0; r < 4; ++r) {
                oacc[2][r] = fmaf(coefA, p0[r], oacc[2][r]);
                oacc[3][r] = fmaf(coefA, p1[r], oacc[3][r]);
            }
        }
        // vg2: vrA = A-g2 -> d-tiles 4,5 ; refill vrA <- B-g0
        {
            f32x4 p0 = __builtin_amdgcn_mfma_f32_16x16x32_bf16(vrA[0].v, bf0, zero, 0, 0, 0);
            p0       = __builtin_amdgcn_mfma_f32_16x16x32_bf16(vrA[1].v, bf1, p0,   0, 0, 0);
            f32x4 p1 = __builtin_amdgcn_mfma_f32_16x16x32_bf16(vrA[2].v, bf0, zero, 0, 0, 0);
            p1       = __builtin_amdgcn_mfma_f32_16x16x32_bf16(vrA[3].v, bf1, p1,   0, 0, 0);
            #pragma unroll
            for (int i = 0; i < 4; ++i) vrA[i].u = vp[baseB + i * 64 + lane];
            __builtin_amdgcn_sched_barrier(0);
            #pragma unroll
            for (int r = 0; r < 4; ++r) {
                oacc[4][r] = fmaf(coefA, p0[r], oacc[4][r]);
                oacc[5][r] = fmaf(coefA, p1[r], oacc[5][r]);
            }
        }
        // vg3: vrB = A-g3 -> d-tiles 6,7 ; refill vrB <- B-g1
        {
            f32x4 p0 = __builtin_amdgcn_mfma_f32_16x16x32_bf16(vrB[0].v, bf0, zero, 0, 0, 0);
            p0       = __builtin_amdgcn_mfma_f32_16x16x32_bf16(vrB[1].v, bf1, p0,   0, 0, 0);
            f32x4 p1 = __builtin_amdgcn_mfma_f32_16x16x32_bf16(vrB[2].v, bf0, zero, 0, 0, 0);
            p1       = __builtin_amdgcn_mfma_f32_16x16x32_bf16(vrB[3].v, bf1, p1,   0, 0, 0);
            #pragma unroll
            for (int i = 0; i < 4; ++i) vrB[i].u = vp[baseB + (4 + i) * 64 + lane];
            __builtin_amdgcn_sched_barrier(0);
            #pragma unroll
            for (int r = 0; r < 4; ++r) {
                oacc[6][r] = fmaf(coefA, p0[r], oacc[6][r]);
                oacc[7][r] = fmaf(coefA, p1[r], oacc[7][r]);
            }
        }
    }

    // ---- PV(B): same bank rotation on block B ----
    {
        const s16x8 bf0 = *(const s16x8*)&PB[n * kPStr + quad * 8];
        const s16x8 bf1 = *(const s16x8*)&PB[n * kPStr + 32 + quad * 8];

        // vg0: vrA = B-g0 -> d-tiles 0,1 ; refill vrA <- B-g2
        {
            f32x4 p0 = __builtin_amdgcn_mfma_f32_16x16x32_bf16(vrA[0].v, bf0, zero, 0, 0, 0);
            p0       = __builtin_amdgcn_mfma_f32_16x16x32_bf16(vrA[1].v, bf1, p0,   0, 0, 0);
            f32x4 p1 = __builtin_amdgcn_mfma_f32_16x16x32_bf16(vrA[2].v, bf0, zero, 0, 0, 0);
            p1       = __builtin_amdgcn_mfma_f32_16x16x32_bf16(vrA[3].v, bf1, p1,   0, 0, 0);
            #pragma unroll
            for (int i = 0; i < 4; ++i) vrA[i].u = vp[baseB + (8 + i) * 64 + lane];
            __builtin_amdgcn_sched_barrier(0);
            #pragma unroll
            for (int r = 0; r < 4; ++r) {
                oacc[0][r] = fmaf(coefB, p0[r], oacc[0][r]);
                oacc[1][r] = fmaf(coefB, p1[r], oacc[1][r]);
            }
        }
        // vg1: vrB = B-g1 -> d-tiles 2,3 ; refill vrB <- B-g3
        {
            f32x4 p0 = __builtin_amdgcn_mfma_f32_16x16x32_bf16(vrB[0].v, bf0, zero, 0, 0, 0);
            p0       = __builtin_amdgcn_mfma_f32_16x16x32_bf16(vrB[1].v, bf1, p0,   0, 0, 0);
            f32x4 p1 = __builtin_amdgcn_mfma_f32_16x16x32_bf16(vrB[2].v, bf0, zero, 0, 0, 0);
            p1       = __builtin_amdgcn_mfma_f32_16x16x32_bf16(vrB[3].v, bf1, p1,   0, 0, 0);
            #pragma unroll
            for (int i = 0; i < 4; ++i) vrB[i].u = vp[baseB + (12 + i) * 64 + lane];
            __builtin_amdgcn_sched_barrier(0);
            #pragma unroll
            for (int r = 0; r < 4; ++r) {
                oacc[2][r] = fmaf(coefB, p0[r], oacc[2][r]);
                oacc[3][r] = fmaf(coefB, p1[r], oacc[3][r]);
            }
        }
        // vg2: vrA = B-g2 -> d-tiles 4,5 (no refill)
        {
            f32x4 p0 = __builtin_amdgcn_mfma_f32_16x16x32_bf16(vrA[0].v, bf0, zero, 0, 0, 0);
            p0       = __builtin_amdgcn_mfma_f32_16x16x32_bf16(vrA[1].v, bf1, p0,   0, 0, 0);
            f32x4 p1 = __builtin_amdgcn_mfma_f32_16x16x32_bf16(vrA[2].v, bf0, zero, 0, 0, 0);
            p1       = __builtin_amdgcn_mfma_f32_16x16x32_bf16(vrA[3].v, bf1, p1,   0, 0, 0);
            #pragma unroll
            for (int r = 0; r < 4; ++r) {
                oacc[4][r] = fmaf(coefB, p0[r], oacc[4][r]);
                oacc[5][r] = fmaf(coefB, p1[r], oacc[5][r]);
            }
        }
        // vg3: vrB = B-g3 -> d-tiles 6,7 (no refill)
        {
            f32x4 p0 = __builtin_amdgcn_mfma_f32_16x16x32_bf16(vrB[0].v, bf0, zero, 0, 0, 0);
            p0       = __builtin_amdgcn_mfma_f32_16x16x32_bf16(vrB[1].v, bf1, p0,   0, 0, 0);
            f32x4 p1 = __builtin_amdgcn_mfma_f32_16x16x32_bf16(vrB[2].v, bf0, zero, 0, 0, 0);
            p1       = __builtin_amdgcn_mfma_f32_16x16x32_bf16(vrB[3].v, bf1, p1,   0, 0, 0);
            #pragma unroll
            for (int r = 0; r < 4; ++r) {
                oacc[6][r] = fmaf(coefB, p0[r], oacc[6][r]);
                oacc[7][r] = fmaf(coefB, p1[r], oacc[7][r]);
            }
        }
    }

    // ---- epilogue: 3-round LDS tree-combine (reuses qf region) ----
    __syncthreads();                       // qf reads done everywhere
    float* epi = (float*)(smem + kQOff);   // 4 slots x 2048 floats

    if (wave >= 4) {
        #pragma unroll
        for (int dt = 0; dt < 8; ++dt)
            *(f32x4*)&epi[(wave - 4) * 2048 + dt * 256 + lane * 4] = oacc[dt];
    }
    __syncthreads();
    if (wave < 4) {
        #pragma unroll
        for (int dt = 0; dt < 8; ++dt) {
            const f32x4 o = *(const f32x4*)&epi[wave * 2048 + dt * 256 + lane * 4];
            #pragma unroll
            for (int r = 0; r < 4; ++r) oacc[dt][r] += o[r];
        }
    }
    __syncthreads();
    if (wave == 2 || wave == 3) {
        #pragma unroll
        for (int dt = 0; dt < 8; ++dt)
            *(f32x4*)&epi[(wave - 2) * 2048 + dt * 256 + lane * 4] = oacc[dt];
    }
    __syncthreads();
    if (wave < 2) {
        #pragma unroll
        for (int dt = 0; dt < 8; ++dt) {
            const f32x4 o = *(const f32x4*)&epi[wave * 2048 + dt * 256 + lane * 4];
            #pragma unroll
            for (int r = 0; r < 4; ++r) oacc[dt][r] += o[r];
        }
    }
    __syncthreads();
    if (wave == 1) {
        #pragma unroll
        for (int dt = 0; dt < 8; ++dt)
            *(f32x4*)&epi[dt * 256 + lane * 4] = oacc[dt];
    }
    __syncthreads();
    if (wave == 0) {
        float* ob = out + ((size_t)l * kHQ + h * kG + n) * kD;
        #pragma unroll
        for (int dt = 0; dt < 8; ++dt) {
            const f32x4 o = *(const f32x4*)&epi[dt * 256 + lane * 4];
            float4 val;
            #pragma unroll
            for (int r = 0; r < 4; ++r) (&val.x)[r] = oacc[dt][r] + o[r];
            *(float4*)(ob + dt * 16 + quad * 4) = val;
        }
    }

    // keep the warm loads alive (no-op, 1 VGPR)
    asm volatile("" :: "v"(warmacc));
}

} // namespace

extern "C" void kernel_launch(void* const* d_in, const int* in_sizes, int n_in,
                              void* d_out, int out_size, void* d_ws, size_t ws_size,
                              hipStream_t stream)
{
    const float* q    = (const float*)d_in[0];
    const float* k    = (const float*)d_in[1];
    const float* v    = (const float*)d_in[2];
    const float* w    = (const float*)d_in[3];
    const int*   bidx = (const int*)d_in[4];
    float* out = (float*)d_out;

    uint4* kp = (uint4*)d_ws;                                   // 2 MB
    uint4* vp = (uint4*)((char*)d_ws + (size_t)kKPackN * 16);   // 2 MB

    pack_kv<<<dim3(512), dim3(256), 0, stream>>>(k, v, kp, vp);
    hsa_main<<<dim3(kLq * kH), dim3(512), 0, stream>>>(q, w, bidx, kp, vp, out);
}